// Round 10
// baseline (334.313 us; speedup 1.0000x reference)
//
#include <hip/hip_runtime.h>

#define NC 91
#define NB 32
#define HW (1024 * 1024)

#define THREADS 256
#define PPT 64                          // pixels per thread
#define PIX_PER_BLOCK (THREADS * PPT)   // 16384
#define CHUNKS (HW / PIX_PER_BLOCK)     // 64 blocks per batch
#define RSTR 92                         // row stride (words): 368 B, 16B-aligned

// Round-10: ABLATION ROUND. Rounds 2-9 falsified every per-pipe model:
// duration (~105 us) is invariant to DS op count (2048/4096/8192 per CU),
// op type (atomic/plain), bank conflicts (0 or 10.5M), occupancy (25-61%).
// This round keeps the round-9 kernel unchanged and appends two full-size
// CONTROL dispatches (results kept alive via asm, outputs unused) so
// rocprof reports each path in isolation:
//   ctrl_mem_kernel: the exact load structure, zero DS  -> memory path alone
//   ctrl_ds_kernel:  the exact DS structure (LCG labels), zero loads -> DS alone
// Readout (pre-committed): mem~105/ds<30 -> memory wall; mem~45/ds~100 ->
// DS wall; both fast -> VMEM-DS interference; both slow -> dual wall.

__global__ __launch_bounds__(256, 4) void hist_kernel(const int* __restrict__ x,
                                                      const int* __restrict__ t,
                                                      int* __restrict__ g_cx,
                                                      int* __restrict__ g_ct,
                                                      int* __restrict__ g_in) {
    __shared__ __align__(16) int s_pair[NC * RSTR];   // 8372 words = 33,488 B

    const int tid = threadIdx.x;
    for (int j = tid; j < NC * RSTR; j += THREADS) s_pair[j] = 0;
    __syncthreads();

    const int b = blockIdx.y;
    const long base = (long)b * HW + (long)blockIdx.x * PIX_PER_BLOCK;
    const int4* __restrict__ x4 = (const int4*)(x + base);
    const int4* __restrict__ t4 = (const int4*)(t + base);

    const int n = PPT / 4;   // 16 iterations, 4 pixels each
    int4 xv0 = x4[tid],           tv0 = t4[tid];
    int4 xv1 = x4[THREADS + tid], tv1 = t4[THREADS + tid];

    for (int i = 0; i < n; ++i) {
        const int pf = (i + 2 < n) ? (i + 2) : (n - 1);   // clamped prefetch
        int4 xn = x4[pf * THREADS + tid];
        int4 tn = t4[pf * THREADS + tid];

        atomicAdd(&s_pair[xv0.x * RSTR + tv0.x], 1);
        atomicAdd(&s_pair[xv0.y * RSTR + tv0.y], 1);
        atomicAdd(&s_pair[xv0.z * RSTR + tv0.z], 1);
        atomicAdd(&s_pair[xv0.w * RSTR + tv0.w], 1);

        xv0 = xv1; tv0 = tv1;
        xv1 = xn;  tv1 = tn;
    }
    __syncthreads();

    if (tid < NC) {
        int ct = 0;
        for (int xx = 0; xx < NC; ++xx) ct += s_pair[xx * RSTR + tid];
        if (ct) atomicAdd(&g_ct[b * NC + tid], ct);
        const int dg = s_pair[tid * RSTR + tid];
        if (dg) atomicAdd(&g_in[b * NC + tid], dg);
    } else if (tid >= 128 && tid < 128 + NC) {
        const int c = tid - 128;
        const int4* row = (const int4*)&s_pair[c * RSTR];
        int cx = 0;
#pragma unroll
        for (int j = 0; j < RSTR / 4; ++j) {
            int4 v = row[j];
            cx += v.x + v.y + v.z + v.w;
        }
        if (cx) atomicAdd(&g_cx[b * NC + c], cx);
    }
}

// CONTROL 1: memory path only — identical grid, loads, prefetch; no DS.
__global__ __launch_bounds__(256, 4) void ctrl_mem_kernel(const int* __restrict__ x,
                                                          const int* __restrict__ t) {
    const int tid = threadIdx.x;
    const int b = blockIdx.y;
    const long base = (long)b * HW + (long)blockIdx.x * PIX_PER_BLOCK;
    const int4* __restrict__ x4 = (const int4*)(x + base);
    const int4* __restrict__ t4 = (const int4*)(t + base);

    const int n = PPT / 4;
    int4 xv0 = x4[tid],           tv0 = t4[tid];
    int4 xv1 = x4[THREADS + tid], tv1 = t4[THREADS + tid];
    int acc = 0;

    for (int i = 0; i < n; ++i) {
        const int pf = (i + 2 < n) ? (i + 2) : (n - 1);
        int4 xn = x4[pf * THREADS + tid];
        int4 tn = t4[pf * THREADS + tid];

        acc += xv0.x + xv0.y + xv0.z + xv0.w;
        acc += tv0.x + tv0.y + tv0.z + tv0.w;

        xv0 = xv1; tv0 = tv1;
        xv1 = xn;  tv1 = tn;
    }
    asm volatile("" :: "v"(acc));   // keep loads live, no output (rule #17)
}

// CONTROL 2: DS path only — identical LDS pair-hist and ds_add count
// (1/pixel, PPT=64), labels from a per-thread LCG; no global loads.
__global__ __launch_bounds__(256, 4) void ctrl_ds_kernel(unsigned seed) {
    __shared__ __align__(16) int s_pair[NC * RSTR];
    const int tid = threadIdx.x;
    for (int j = tid; j < NC * RSTR; j += THREADS) s_pair[j] = 0;
    __syncthreads();

    unsigned h = seed ^ (blockIdx.x * 9781u) ^ (blockIdx.y * 6271u)
                 ^ (tid * 2654435761u);
#pragma unroll 4
    for (int i = 0; i < PPT; ++i) {
        h = h * 1664525u + 1013904223u;
        const int xx = (h >> 8) & 63;    // 64-class scatter ~ the real 91-class
        const int tt = (h >> 20) & 63;
        atomicAdd(&s_pair[xx * RSTR + tt], 1);
    }
    __syncthreads();

    int v = s_pair[tid * 29 % (NC * RSTR)];
    asm volatile("" :: "v"(v));         // keep the histogram live
}

__global__ __launch_bounds__(64) void finalize_kernel(const int* __restrict__ g_cx,
                                                      const int* __restrict__ g_ct,
                                                      const int* __restrict__ g_in,
                                                      const float* __restrict__ smooth,
                                                      float* __restrict__ out) {
    const int b = blockIdx.x;
    const int lane = threadIdx.x;  // 0..63
    const float s = smooth[0];
    float acc = 0.0f;
    for (int c = lane; c < NC; c += 64) {
        const float in = (float)g_in[b * NC + c];
        const float un = (float)(g_cx[b * NC + c] + g_ct[b * NC + c]) - in;
        acc += (in + s) / (un + s);
    }
#pragma unroll
    for (int off = 32; off > 0; off >>= 1)
        acc += __shfl_down(acc, off, 64);
    if (lane == 0) out[b] = acc / (float)NC;
}

extern "C" void kernel_launch(void* const* d_in, const int* in_sizes, int n_in,
                              void* d_out, int out_size, void* d_ws, size_t ws_size,
                              hipStream_t stream) {
    const int* x = (const int*)d_in[0];
    const int* t = (const int*)d_in[1];
    const float* smooth = (const float*)d_in[2];
    float* out = (float*)d_out;

    int* g_cx = (int*)d_ws;                   // NB*NC
    int* g_ct = g_cx + NB * NC;               // NB*NC
    int* g_in = g_ct + NB * NC;               // NB*NC

    hipMemsetAsync(d_ws, 0, 3 * NB * NC * sizeof(int), stream);

    dim3 grid(CHUNKS, NB);  // 64 x 32 = 2048 blocks
    hist_kernel<<<grid, THREADS, 0, stream>>>(x, t, g_cx, g_ct, g_in);
    finalize_kernel<<<NB, 64, 0, stream>>>(g_cx, g_ct, g_in, smooth, out);

    // Controls run after the answer is produced; full-size for comparability.
    ctrl_mem_kernel<<<grid, THREADS, 0, stream>>>(x, t);
    ctrl_ds_kernel<<<grid, THREADS, 0, stream>>>(0x12345u);
}

// Round 12
// 284.269 us; speedup vs baseline: 1.1760x; 1.1760x over previous
//
#include <hip/hip_runtime.h>

#define NC 91
#define NB 32
#define HW (1024 * 1024)

#define THREADS 256
#define PPT 64                          // pixels per thread
#define PIX_PER_BLOCK (THREADS * PPT)   // 16384
#define CHUNKS (HW / PIX_PER_BLOCK)     // 64 blocks per batch
#define NPAIR (NC * NC)                 // 8281 joint bins
#define NWORD ((NPAIR + 1) / 2)         // 4141 packed words = 16,564 B

// Round-12 (= round-11 resubmitted; infra failed, kernel never measured).
// Pair histogram (1 ds_add/pixel, round-9) + 16-bit field packing to halve
// LDS and restore occupancy. Round-10 ablation: mem-path alone ~42 us
// (no LDS, 8 blocks/CU), DS alone ~10 us, combined 102 us at 4 blocks/CU
// -> the ~105 us invariant was MEMORY-LATENCY EXPOSURE at LDS-capped
// occupancy (T_mem ~ 42us x 32/waves), not a DS wall.
// Packing: bin b -> word b>>1, field (b&1)*16. Max count per bin per block
// = 16384 < 2^16: no overflow, no cross-field carry. 16.6 KB -> 8 blocks/CU
// (32 waves, 100%). Same proven depth-2 int4 prefetch.

__global__ __launch_bounds__(256, 8) void hist_kernel(const int* __restrict__ x,
                                                      const int* __restrict__ t,
                                                      int* __restrict__ g_cx,
                                                      int* __restrict__ g_ct,
                                                      int* __restrict__ g_in) {
    __shared__ int s_pair[NWORD];   // 16,564 B, 2 bins/word (16-bit fields)

    const int tid = threadIdx.x;
    for (int j = tid; j < NWORD; j += THREADS) s_pair[j] = 0;
    __syncthreads();

    const int b = blockIdx.y;
    const long base = (long)b * HW + (long)blockIdx.x * PIX_PER_BLOCK;
    const int4* __restrict__ x4 = (const int4*)(x + base);
    const int4* __restrict__ t4 = (const int4*)(t + base);

    const int n = PPT / 4;   // 16 iterations, 4 pixels each
    int4 xv0 = x4[tid],           tv0 = t4[tid];
    int4 xv1 = x4[THREADS + tid], tv1 = t4[THREADS + tid];

    for (int i = 0; i < n; ++i) {
        const int pf = (i + 2 < n) ? (i + 2) : (n - 1);   // clamped prefetch
        int4 xn = x4[pf * THREADS + tid];
        int4 tn = t4[pf * THREADS + tid];

        // one fire-and-forget ds_add per pixel, 16-bit packed field
        const int b0 = xv0.x * NC + tv0.x;
        const int b1 = xv0.y * NC + tv0.y;
        const int b2 = xv0.z * NC + tv0.z;
        const int b3 = xv0.w * NC + tv0.w;
        atomicAdd(&s_pair[b0 >> 1], 1 << ((b0 & 1) << 4));
        atomicAdd(&s_pair[b1 >> 1], 1 << ((b1 & 1) << 4));
        atomicAdd(&s_pair[b2 >> 1], 1 << ((b2 & 1) << 4));
        atomicAdd(&s_pair[b3 >> 1], 1 << ((b3 & 1) << 4));

        xv0 = xv1; tv0 = tv1;
        xv1 = xn;  tv1 = tn;
    }
    __syncthreads();

    // Epilogue: fold the packed joint histogram into its three marginals.
    // threads 0..90: column sums (cnt_t) + diagonal (inter).
    if (tid < NC) {
        int ct = 0;
        for (int xx = 0; xx < NC; ++xx) {
            const int bin = xx * NC + tid;
            ct += (s_pair[bin >> 1] >> ((bin & 1) << 4)) & 0xffff;
        }
        if (ct) atomicAdd(&g_ct[b * NC + tid], ct);
        // diag bin = tid*(NC+1) = tid*92: always even parity -> lo field
        const int dg = s_pair[tid * 46] & 0xffff;
        if (dg) atomicAdd(&g_in[b * NC + tid], dg);
    }
    // threads 128..218: row sums (cnt_x), bins contiguous.
    else if (tid >= 128 && tid < 128 + NC) {
        const int c = tid - 128;
        int cx = 0;
        for (int tt = 0; tt < NC; ++tt) {
            const int bin = c * NC + tt;
            cx += (s_pair[bin >> 1] >> ((bin & 1) << 4)) & 0xffff;
        }
        if (cx) atomicAdd(&g_cx[b * NC + c], cx);
    }
}

__global__ __launch_bounds__(64) void finalize_kernel(const int* __restrict__ g_cx,
                                                      const int* __restrict__ g_ct,
                                                      const int* __restrict__ g_in,
                                                      const float* __restrict__ smooth,
                                                      float* __restrict__ out) {
    const int b = blockIdx.x;
    const int lane = threadIdx.x;  // 0..63
    const float s = smooth[0];
    float acc = 0.0f;
    for (int c = lane; c < NC; c += 64) {
        const float in = (float)g_in[b * NC + c];
        const float un = (float)(g_cx[b * NC + c] + g_ct[b * NC + c]) - in;
        acc += (in + s) / (un + s);
    }
#pragma unroll
    for (int off = 32; off > 0; off >>= 1)
        acc += __shfl_down(acc, off, 64);
    if (lane == 0) out[b] = acc / (float)NC;
}

extern "C" void kernel_launch(void* const* d_in, const int* in_sizes, int n_in,
                              void* d_out, int out_size, void* d_ws, size_t ws_size,
                              hipStream_t stream) {
    const int* x = (const int*)d_in[0];
    const int* t = (const int*)d_in[1];
    const float* smooth = (const float*)d_in[2];
    float* out = (float*)d_out;

    int* g_cx = (int*)d_ws;                   // NB*NC
    int* g_ct = g_cx + NB * NC;               // NB*NC
    int* g_in = g_ct + NB * NC;               // NB*NC

    hipMemsetAsync(d_ws, 0, 3 * NB * NC * sizeof(int), stream);

    dim3 grid(CHUNKS, NB);  // 64 x 32 = 2048 blocks (8/CU, one full round)
    hist_kernel<<<grid, THREADS, 0, stream>>>(x, t, g_cx, g_ct, g_in);
    finalize_kernel<<<NB, 64, 0, stream>>>(g_cx, g_ct, g_in, smooth, out);
}